// Round 1
// baseline (3627.485 us; speedup 1.0000x reference)
//
#include <hip/hip_runtime.h>

// SubgraphPooling: out[s, :] = mean over edges e with seg[e]==s of feat[nid[e], :]
// N_NODES=100000, D=128, N_GATHER=2000000, N_SEGMENTS=250000

constexpr int D_FEAT   = 128;
constexpr int N_SEG    = 250000;

// 32 lanes per edge; each lane handles one float4 (4 features).
__global__ __launch_bounds__(256) void sp_scatter(
    const float4* __restrict__ feat,   // [N_NODES][32] as float4
    const int*    __restrict__ nid,    // [E]
    const int*    __restrict__ sid,    // [E]
    float*        __restrict__ out,    // [N_SEG][128] accumulator (pre-zeroed)
    float*        __restrict__ cnt,    // [N_SEG] (pre-zeroed)
    int n_edges)
{
    int t    = blockIdx.x * blockDim.x + threadIdx.x;
    int edge = t >> 5;          // 32 threads per edge
    int c    = t & 31;          // float4 chunk index within feature row
    if (edge >= n_edges) return;

    int node = nid[edge];
    int seg  = sid[edge];

    float4 v = feat[(size_t)node * 32 + c];
    float* o = out + (size_t)seg * D_FEAT + c * 4;
    atomicAdd(o + 0, v.x);
    atomicAdd(o + 1, v.y);
    atomicAdd(o + 2, v.z);
    atomicAdd(o + 3, v.w);
    if (c == 0) atomicAdd(&cnt[seg], 1.0f);
}

__global__ __launch_bounds__(256) void sp_divide(
    float4* __restrict__ out,          // [N_SEG*32] float4
    const float* __restrict__ cnt)
{
    int t = blockIdx.x * blockDim.x + threadIdx.x;
    int seg = t >> 5;
    if (seg >= N_SEG) return;
    float inv = 1.0f / fmaxf(cnt[seg], 1.0f);
    float4 v = out[t];
    v.x *= inv; v.y *= inv; v.z *= inv; v.w *= inv;
    out[t] = v;
}

extern "C" void kernel_launch(void* const* d_in, const int* in_sizes, int n_in,
                              void* d_out, int out_size, void* d_ws, size_t ws_size,
                              hipStream_t stream) {
    const float* feat = (const float*)d_in[0];
    const int*   nid  = (const int*)d_in[1];
    const int*   sid  = (const int*)d_in[2];
    float*       out  = (float*)d_out;
    float*       cnt  = (float*)d_ws;

    const int n_edges = in_sizes[1];

    // Accumulators must start at zero every call (harness poisons to 0xAA).
    hipMemsetAsync(d_out, 0, (size_t)out_size * sizeof(float), stream);
    hipMemsetAsync(d_ws, 0, (size_t)N_SEG * sizeof(float), stream);

    {
        long long threads = (long long)n_edges * 32;
        int blocks = (int)((threads + 255) / 256);
        sp_scatter<<<blocks, 256, 0, stream>>>((const float4*)feat, nid, sid,
                                               out, cnt, n_edges);
    }
    {
        long long threads = (long long)N_SEG * 32;
        int blocks = (int)((threads + 255) / 256);
        sp_divide<<<blocks, 256, 0, stream>>>((float4*)out, cnt);
    }
}

// Round 2
// 501.040 us; speedup vs baseline: 7.2399x; 7.2399x over previous
//
#include <hip/hip_runtime.h>

// SubgraphPooling via counting-sort + segmented reduction (no fp32 atomics).
// out[s,:] = mean over edges e with sid[e]==s of feat[nid[e],:]
// N_NODES=100000, D=128, E=2000000, N_SEG=250000

constexpr int D_FEAT = 128;
constexpr int N_SEG  = 250000;
constexpr int SCAN_CHUNK = 1024;                       // elems per scan block (256 thr x 4)
constexpr int SCAN_BLOCKS = (N_SEG + SCAN_CHUNK - 1) / SCAN_CHUNK;  // 245

// ---- workspace layout (bytes) ----
// [0,      1MB)  cnt_i   int[N_SEG]
// [1MB,    2MB)  offsets int[N_SEG]
// [2MB,    3MB)  cursor  int[N_SEG]
// [3MB,   3MB+1KB) blockSums int[SCAN_BLOCKS]
// [4MB,   12MB)  sorted_nid int[E]
#define WS_CNT(ws)     ((int*)((char*)(ws) + 0))
#define WS_OFF(ws)     ((int*)((char*)(ws) + (1u<<20)))
#define WS_CUR(ws)     ((int*)((char*)(ws) + (2u<<20)))
#define WS_BSUM(ws)    ((int*)((char*)(ws) + (3u<<20)))
#define WS_SORTED(ws)  ((int*)((char*)(ws) + (4u<<20)))

__global__ __launch_bounds__(256) void sp_hist(
    const int* __restrict__ sid, int* __restrict__ cnt, int n)
{
    int i = blockIdx.x * blockDim.x + threadIdx.x;
    if (i < n) atomicAdd(&cnt[sid[i]], 1);
}

// Phase A: per-block exclusive scan over 1024-elem chunks; emit block totals.
__global__ __launch_bounds__(256) void sp_scan_local(
    const int* __restrict__ cnt, int* __restrict__ off, int* __restrict__ bsum)
{
    __shared__ int sh[256];
    int tid  = threadIdx.x;
    int base = blockIdx.x * SCAN_CHUNK + tid * 4;
    int v0 = (base + 0 < N_SEG) ? cnt[base + 0] : 0;
    int v1 = (base + 1 < N_SEG) ? cnt[base + 1] : 0;
    int v2 = (base + 2 < N_SEG) ? cnt[base + 2] : 0;
    int v3 = (base + 3 < N_SEG) ? cnt[base + 3] : 0;
    sh[tid] = v0 + v1 + v2 + v3;
    __syncthreads();
    // Hillis-Steele inclusive scan over 256 thread sums
    for (int o = 1; o < 256; o <<= 1) {
        int t = (tid >= o) ? sh[tid - o] : 0;
        __syncthreads();
        sh[tid] += t;
        __syncthreads();
    }
    int excl = (tid > 0) ? sh[tid - 1] : 0;
    if (base + 0 < N_SEG) off[base + 0] = excl;
    if (base + 1 < N_SEG) off[base + 1] = excl + v0;
    if (base + 2 < N_SEG) off[base + 2] = excl + v0 + v1;
    if (base + 3 < N_SEG) off[base + 3] = excl + v0 + v1 + v2;
    if (tid == 255) bsum[blockIdx.x] = sh[255];
}

// Phase B: exclusive scan of the 245 block totals (single thread; trivial).
__global__ void sp_scan_blocks(int* __restrict__ bsum)
{
    if (threadIdx.x == 0 && blockIdx.x == 0) {
        int acc = 0;
        for (int i = 0; i < SCAN_BLOCKS; ++i) { int t = bsum[i]; bsum[i] = acc; acc += t; }
    }
}

// Phase C: add block bases back.
__global__ __launch_bounds__(256) void sp_scan_add(
    int* __restrict__ off, const int* __restrict__ bsum)
{
    int i = blockIdx.x * blockDim.x + threadIdx.x;
    if (i < N_SEG) off[i] += bsum[i / SCAN_CHUNK];
}

// Reorder: place each edge's node id into its segment's contiguous range.
__global__ __launch_bounds__(256) void sp_reorder(
    const int* __restrict__ nid, const int* __restrict__ sid,
    const int* __restrict__ off, int* __restrict__ cur,
    int* __restrict__ sorted_nid, int n)
{
    int i = blockIdx.x * blockDim.x + threadIdx.x;
    if (i >= n) return;
    int s = sid[i];
    int pos = off[s] + atomicAdd(&cur[s], 1);
    sorted_nid[pos] = nid[i];
}

// Reduce: one wave (64 lanes) per segment; lane handles 2 features (float2).
__global__ __launch_bounds__(256) void sp_reduce(
    const float2* __restrict__ feat2,      // [N_NODES][64] float2
    const int* __restrict__ sorted_nid,
    const int* __restrict__ off,
    const int* __restrict__ cnt,
    float2* __restrict__ out2)             // [N_SEG][64] float2
{
    int wave = blockIdx.x * 4 + (threadIdx.x >> 6);
    int lane = threadIdx.x & 63;
    if (wave >= N_SEG) return;

    int n   = cnt[wave];
    int beg = off[wave];

    float2 acc = make_float2(0.f, 0.f);
    int j = 0;
    for (; j + 1 < n; j += 2) {                     // 2-deep for MLP
        int n0 = sorted_nid[beg + j];
        int n1 = sorted_nid[beg + j + 1];
        float2 a = feat2[(size_t)n0 * 64 + lane];
        float2 b = feat2[(size_t)n1 * 64 + lane];
        acc.x += a.x + b.x;
        acc.y += a.y + b.y;
    }
    if (j < n) {
        int n0 = sorted_nid[beg + j];
        float2 a = feat2[(size_t)n0 * 64 + lane];
        acc.x += a.x;
        acc.y += a.y;
    }
    float inv = 1.0f / (float)max(n, 1);
    out2[(size_t)wave * 64 + lane] = make_float2(acc.x * inv, acc.y * inv);
}

extern "C" void kernel_launch(void* const* d_in, const int* in_sizes, int n_in,
                              void* d_out, int out_size, void* d_ws, size_t ws_size,
                              hipStream_t stream) {
    const float* feat = (const float*)d_in[0];
    const int*   nid  = (const int*)d_in[1];
    const int*   sid  = (const int*)d_in[2];
    const int n_edges = in_sizes[1];

    int* cnt    = WS_CNT(d_ws);
    int* off    = WS_OFF(d_ws);
    int* cur    = WS_CUR(d_ws);
    int* bsum   = WS_BSUM(d_ws);
    int* sorted = WS_SORTED(d_ws);

    // zero counters + cursors (harness poisons ws to 0xAA)
    hipMemsetAsync(cnt, 0, (size_t)N_SEG * sizeof(int), stream);
    hipMemsetAsync(cur, 0, (size_t)N_SEG * sizeof(int), stream);

    int eb = (n_edges + 255) / 256;
    sp_hist<<<eb, 256, 0, stream>>>(sid, cnt, n_edges);
    sp_scan_local<<<SCAN_BLOCKS, 256, 0, stream>>>(cnt, off, bsum);
    sp_scan_blocks<<<1, 64, 0, stream>>>(bsum);
    sp_scan_add<<<(N_SEG + 255) / 256, 256, 0, stream>>>(off, bsum);
    sp_reorder<<<eb, 256, 0, stream>>>(nid, sid, off, cur, sorted, n_edges);

    int rb = (N_SEG + 3) / 4;   // 4 waves (segments) per 256-thread block
    sp_reduce<<<rb, 256, 0, stream>>>((const float2*)feat, sorted, off, cnt,
                                      (float2*)d_out);
}

// Round 4
// 481.274 us; speedup vs baseline: 7.5373x; 1.0411x over previous
//
#include <hip/hip_runtime.h>

// SubgraphPooling via counting-sort + segmented reduction (no fp32 atomics).
// out[s,:] = mean over edges e with sid[e]==s of feat[nid[e],:]
// N_NODES=100000, D=128, E=2000000, N_SEG=250000

constexpr int D_FEAT = 128;
constexpr int N_SEG  = 250000;
constexpr int SCAN_CHUNK  = 1024;                                   // 256 thr x 4
constexpr int SCAN_BLOCKS = (N_SEG + SCAN_CHUNK - 1) / SCAN_CHUNK;  // 245

// ---- workspace layout (bytes) ----
// [0,    1MB)  cnt   int[N_SEG]
// [1MB,  2MB)  cur   int[N_SEG]
// [2MB,  3MB)  off   int[N_SEG]     (chunk-local exclusive prefix)
// [3MB,  3MB+1KB) bsum int[SCAN_BLOCKS] (chunk base after scan)
// [4MB, 12MB)  sorted_nid int[E]
#define WS_CNT(ws)     ((int*)((char*)(ws) + 0))
#define WS_CUR(ws)     ((int*)((char*)(ws) + (1u<<20)))
#define WS_OFF(ws)     ((int*)((char*)(ws) + (2u<<20)))
#define WS_BSUM(ws)    ((int*)((char*)(ws) + (3u<<20)))
#define WS_SORTED(ws)  ((int*)((char*)(ws) + (4u<<20)))

__global__ __launch_bounds__(256) void sp_hist(
    const int* __restrict__ sid, int* __restrict__ cnt, int n)
{
    int i = blockIdx.x * blockDim.x + threadIdx.x;
    if (i < n) atomicAdd(&cnt[sid[i]], 1);
}

// Per-chunk exclusive scan (1024 elems / block); emit chunk totals.
__global__ __launch_bounds__(256) void sp_scan_local(
    const int* __restrict__ cnt, int* __restrict__ off, int* __restrict__ bsum)
{
    __shared__ int sh[256];
    int tid  = threadIdx.x;
    int base = blockIdx.x * SCAN_CHUNK + tid * 4;
    int v0 = (base + 0 < N_SEG) ? cnt[base + 0] : 0;
    int v1 = (base + 1 < N_SEG) ? cnt[base + 1] : 0;
    int v2 = (base + 2 < N_SEG) ? cnt[base + 2] : 0;
    int v3 = (base + 3 < N_SEG) ? cnt[base + 3] : 0;
    sh[tid] = v0 + v1 + v2 + v3;
    __syncthreads();
    for (int o = 1; o < 256; o <<= 1) {
        int t = (tid >= o) ? sh[tid - o] : 0;
        __syncthreads();
        sh[tid] += t;
        __syncthreads();
    }
    int excl = (tid > 0) ? sh[tid - 1] : 0;
    if (base + 0 < N_SEG) off[base + 0] = excl;
    if (base + 1 < N_SEG) off[base + 1] = excl + v0;
    if (base + 2 < N_SEG) off[base + 2] = excl + v0 + v1;
    if (base + 3 < N_SEG) off[base + 3] = excl + v0 + v1 + v2;
    if (tid == 255) bsum[blockIdx.x] = sh[255];
}

// Exclusive scan of the 245 chunk totals — one block, LDS scan (parallel).
__global__ __launch_bounds__(256) void sp_scan_blocks(int* __restrict__ bsum)
{
    __shared__ int sh[256];
    int tid = threadIdx.x;
    int v = (tid < SCAN_BLOCKS) ? bsum[tid] : 0;
    sh[tid] = v;
    __syncthreads();
    for (int o = 1; o < 256; o <<= 1) {
        int t = (tid >= o) ? sh[tid - o] : 0;
        __syncthreads();
        sh[tid] += t;
        __syncthreads();
    }
    if (tid < SCAN_BLOCKS) bsum[tid] = sh[tid] - v;   // inclusive -> exclusive
}

// Reorder: place each edge's node id into its segment's contiguous range.
// Global offset = chunk-local off[s] + chunk base bsum[s>>10].
__global__ __launch_bounds__(256) void sp_reorder(
    const int* __restrict__ nid, const int* __restrict__ sid,
    const int* __restrict__ off, const int* __restrict__ bsum,
    int* __restrict__ cur, int* __restrict__ sorted_nid, int n)
{
    int i = blockIdx.x * blockDim.x + threadIdx.x;
    if (i >= n) return;
    int s = sid[i];
    int pos = off[s] + bsum[s >> 10] + atomicAdd(&cur[s], 1);
    sorted_nid[pos] = nid[i];
}

// Reduce: one half-wave (32 lanes) per segment; lane = one float4 chunk.
// Edge ids preloaded into registers (one coalesced load), broadcast via shfl
// so the inner loop's only global dependency is the feat row load.
__global__ __launch_bounds__(256) void sp_reduce(
    const float4* __restrict__ feat4,      // [N_NODES][32] float4
    const int* __restrict__ sorted_nid,
    const int* __restrict__ off,
    const int* __restrict__ bsum,
    const int* __restrict__ cnt,
    float4* __restrict__ out4)             // [N_SEG][32] float4
{
    int seg  = blockIdx.x * 8 + (threadIdx.x >> 5);
    int lane = threadIdx.x & 31;
    if (seg >= N_SEG) return;

    int n   = cnt[seg];
    int beg = off[seg] + bsum[seg >> 10];

    int myid = (lane < n) ? sorted_nid[beg + lane] : 0;

    float4 acc0 = make_float4(0.f, 0.f, 0.f, 0.f);
    float4 acc1 = make_float4(0.f, 0.f, 0.f, 0.f);
    int m = (n < 32) ? n : 32;
    int j = 0;
    for (; j + 1 < m; j += 2) {
        int n0 = __shfl(myid, j,     32);
        int n1 = __shfl(myid, j + 1, 32);
        float4 a = feat4[(size_t)n0 * 32 + lane];
        float4 b = feat4[(size_t)n1 * 32 + lane];
        acc0.x += a.x; acc0.y += a.y; acc0.z += a.z; acc0.w += a.w;
        acc1.x += b.x; acc1.y += b.y; acc1.z += b.z; acc1.w += b.w;
    }
    if (j < m) {
        int n0 = __shfl(myid, j, 32);
        float4 a = feat4[(size_t)n0 * 32 + lane];
        acc0.x += a.x; acc0.y += a.y; acc0.z += a.z; acc0.w += a.w;
    }
    // pathological n > 32 fallback (Poisson(8): effectively never)
    for (int k = 32; k < n; ++k) {
        int nk = sorted_nid[beg + k];
        float4 a = feat4[(size_t)nk * 32 + lane];
        acc0.x += a.x; acc0.y += a.y; acc0.z += a.z; acc0.w += a.w;
    }

    float inv = 1.0f / (float)max(n, 1);
    float4 r;
    r.x = (acc0.x + acc1.x) * inv;
    r.y = (acc0.y + acc1.y) * inv;
    r.z = (acc0.z + acc1.z) * inv;
    r.w = (acc0.w + acc1.w) * inv;
    out4[(size_t)seg * 32 + lane] = r;
}

extern "C" void kernel_launch(void* const* d_in, const int* in_sizes, int n_in,
                              void* d_out, int out_size, void* d_ws, size_t ws_size,
                              hipStream_t stream) {
    const float* feat = (const float*)d_in[0];
    const int*   nid  = (const int*)d_in[1];
    const int*   sid  = (const int*)d_in[2];
    const int n_edges = in_sizes[1];

    int* cnt    = WS_CNT(d_ws);
    int* cur    = WS_CUR(d_ws);
    int* off    = WS_OFF(d_ws);
    int* bsum   = WS_BSUM(d_ws);
    int* sorted = WS_SORTED(d_ws);

    // Zero the FULL [0, 2MiB) range: cnt and cur live in 1MiB-aligned slots
    // (R3 bug: 2*N_SEG*4 bytes left the tail of cur poisoned -> OOB fault).
    hipMemsetAsync(d_ws, 0, (size_t)(2u << 20), stream);

    int eb = (n_edges + 255) / 256;
    sp_hist<<<eb, 256, 0, stream>>>(sid, cnt, n_edges);
    sp_scan_local<<<SCAN_BLOCKS, 256, 0, stream>>>(cnt, off, bsum);
    sp_scan_blocks<<<1, 256, 0, stream>>>(bsum);
    sp_reorder<<<eb, 256, 0, stream>>>(nid, sid, off, bsum, cur, sorted, n_edges);

    int rb = (N_SEG + 7) / 8;   // 8 segments (half-waves) per 256-thread block
    sp_reduce<<<rb, 256, 0, stream>>>((const float4*)feat, sorted, off, bsum,
                                      cnt, (float4*)d_out);
}